// Round 2
// baseline (379.095 us; speedup 1.0000x reference)
//
#include <hip/hip_runtime.h>

// ---------------------------------------------------------------------------
// CormorantCGProduct on MI355X.
// Inputs (setup_inputs dict order — INTERLEAVED): A0,B0,A1,B1,A2,B2,A3,B3,
//   each fp32 shape (2, N, 2l+1, 16).
// Output: concat over l=0..3 of (2, N, 2l+1, CH_l) with CH_l = 256*npairs_l
//         (pairs in l1-major, l2-minor order, channels laid out c*16+d).
// Strategy: store-BW-bound (327 MB out vs 4 MB in). One thread per float4 of
// output channels; each wave writes one contiguous 1KB chunk per store.
// CG coefficients computed on-device each call into d_ws (graph-capture safe).
// ---------------------------------------------------------------------------

__device__ inline double dfact(int n) {
    double r = 1.0;
    for (int i = 2; i <= n; ++i) r *= (double)i;
    return r;
}

// Clebsch-Gordan <j1 m1 j2 m2 | j m>, Condon-Shortley, exactly as reference.
__device__ double cg_coef(int j1, int m1, int j2, int m2, int j, int m) {
    if (m1 + m2 != m) return 0.0;
    double pref = sqrt((double)(2 * j + 1)
        * dfact(j + j1 - j2) * dfact(j - j1 + j2) * dfact(j1 + j2 - j)
        / dfact(j1 + j2 + j + 1)
        * dfact(j + m) * dfact(j - m) * dfact(j1 - m1) * dfact(j1 + m1)
        * dfact(j2 - m2) * dfact(j2 + m2));
    int kmin = 0;
    if (j2 - j - m1 > kmin) kmin = j2 - j - m1;
    if (j1 - j + m2 > kmin) kmin = j1 - j + m2;
    int kmax = j1 + j2 - j;
    if (j1 - m1 < kmax) kmax = j1 - m1;
    if (j2 + m2 < kmax) kmax = j2 + m2;
    double s = 0.0;
    for (int k = kmin; k <= kmax; ++k) {
        double d = dfact(k) * dfact(j1 + j2 - j - k) * dfact(j1 - m1 - k)
                 * dfact(j2 + m2 - k) * dfact(j - j2 + m1 + k)
                 * dfact(j - j1 - m2 + k);
        s += (k & 1) ? (-1.0 / d) : (1.0 / d);
    }
    return pref * s;
}

// Writes all dense CG matrices, triple-loop order (l1, l2, l), into cgbuf.
// Total entries: 3436 floats (~13.7 KB).
__global__ void cg_init_kernel(float* __restrict__ cgbuf) {
    int tid = blockIdx.x * blockDim.x + threadIdx.x;
    int off = 0;
    for (int l1 = 0; l1 <= 3; ++l1)
    for (int l2 = 0; l2 <= 3; ++l2) {
        int lo = (l1 > l2) ? (l1 - l2) : (l2 - l1);
        int hi = (l1 + l2 < 3) ? (l1 + l2) : 3;
        for (int l = lo; l <= hi; ++l) {
            int xd = 2 * l1 + 1, yd = 2 * l2 + 1, zd = 2 * l + 1;
            int sz = xd * yd * zd;
            if (tid >= off && tid < off + sz) {
                int e = tid - off;
                int z = e % zd;
                int xy = e / zd;
                int y = xy % yd;
                int x = xy / yd;
                int m1 = x - l1, m2 = y - l2, m = z - l;
                double val = 0.0;
                if (m1 + m2 == m) val = cg_coef(l1, m1, l2, m2, l, m);
                cgbuf[tid] = (float)val;
            }
            off += sz;
        }
    }
}

// One kernel per output degree L. Thread t handles one float4 (4 consecutive
// channels) of real + imag for a (pair-segment, n, z).
template <int L>
__global__ __launch_bounds__(256) void cg_prod_kernel(
    const float* __restrict__ A0, const float* __restrict__ A1,
    const float* __restrict__ A2, const float* __restrict__ A3,
    const float* __restrict__ B0, const float* __restrict__ B1,
    const float* __restrict__ B2, const float* __restrict__ B3,
    const float* __restrict__ cgbuf,
    float* __restrict__ out,
    int N, long outBase, int CHL)
{
    constexpr int zdim = 2 * L + 1;

    __shared__ int sh_l1, sh_l2, sh_c0, sh_cg;
    __shared__ long sh_qs;
    if (threadIdx.x == 0) {
        long q = (long)blockIdx.x * 256;
        long acc = 0;
        int cg = 0, c0 = 0;
        int fl1 = 0, fl2 = 0, fc0 = 0, fcg = 0;
        long fqs = 0;
        for (int l1 = 0; l1 <= 3; ++l1)
        for (int l2 = 0; l2 <= 3; ++l2) {
            int lo = (l1 > l2) ? (l1 - l2) : (l2 - l1);
            int hi = (l1 + l2 < 3) ? (l1 + l2) : 3;
            for (int l = lo; l <= hi; ++l) {
                if (l == L) {
                    long nq = (long)N * zdim * 64;
                    if (q >= acc && q < acc + nq) {
                        fl1 = l1; fl2 = l2; fc0 = c0; fcg = cg; fqs = acc;
                    }
                    acc += nq;
                    c0 += 256;
                }
                cg += (2 * l1 + 1) * (2 * l2 + 1) * (2 * l + 1);
            }
        }
        sh_l1 = fl1; sh_l2 = fl2; sh_c0 = fc0; sh_cg = fcg; sh_qs = fqs;
    }
    __syncthreads();

    const int l1 = sh_l1, l2 = sh_l2;
    const int xdim = 2 * l1 + 1, ydim = 2 * l2 + 1;
    const float* Abase = (l1 == 0) ? A0 : (l1 == 1) ? A1 : (l1 == 2) ? A2 : A3;
    const float* Bbase = (l2 == 0) ? B0 : (l2 == 1) ? B1 : (l2 == 2) ? B2 : B3;

    unsigned v = (unsigned)((long)blockIdx.x * 256 + threadIdx.x - sh_qs);
    const int cd4 = v & 63;       // which float4 within the 256-channel block
    v >>= 6;
    const int n = v / zdim;       // compile-time-constant divisor
    const int z = v - n * zdim;
    const int c = cd4 >> 2;       // tau1 index
    const int d4 = (cd4 & 3) << 2;// tau2 start

    const float* Ar = Abase + (long)n * xdim * 16 + c;      // stride 16 over x
    const float* Ai = Ar + (long)N * xdim * 16;
    const float* Br = Bbase + (long)n * ydim * 16 + d4;     // float4 per y
    const float* Bi = Br + (long)N * ydim * 16;
    const float* CG = cgbuf + sh_cg + z;                    // + (x*ydim+y)*zdim

    // y = s - x must lie in [0, ydim)
    const int s = z + l1 + l2 - L;
    int xlo = s - (ydim - 1); if (xlo < 0) xlo = 0;
    int xhi = (s < xdim - 1) ? s : (xdim - 1);

    float4 accr = make_float4(0.f, 0.f, 0.f, 0.f);
    float4 acci = make_float4(0.f, 0.f, 0.f, 0.f);
    for (int x = xlo; x <= xhi; ++x) {
        const int y = s - x;
        const float cgv = CG[(x * ydim + y) * zdim];
        const float arv = Ar[x * 16];
        const float aiv = Ai[x * 16];
        const float4 br = *reinterpret_cast<const float4*>(Br + y * 16);
        const float4 bi = *reinterpret_cast<const float4*>(Bi + y * 16);
        accr.x += cgv * (arv * br.x - aiv * bi.x);
        accr.y += cgv * (arv * br.y - aiv * bi.y);
        accr.z += cgv * (arv * br.z - aiv * bi.z);
        accr.w += cgv * (arv * br.w - aiv * bi.w);
        acci.x += cgv * (arv * bi.x + aiv * br.x);
        acci.y += cgv * (arv * bi.y + aiv * br.y);
        acci.z += cgv * (arv * bi.z + aiv * br.z);
        acci.w += cgv * (arv * bi.w + aiv * br.w);
    }

    const long off = outBase + ((long)n * zdim + z) * (long)CHL + sh_c0 + cd4 * 4;
    *reinterpret_cast<float4*>(out + off) = accr;
    *reinterpret_cast<float4*>(out + off + (long)N * zdim * CHL) = acci;
}

extern "C" void kernel_launch(void* const* d_in, const int* in_sizes, int n_in,
                              void* d_out, int out_size, void* d_ws, size_t ws_size,
                              hipStream_t stream) {
    // setup_inputs() dict order is INTERLEAVED: A0,B0,A1,B1,A2,B2,A3,B3
    const float* A0 = (const float*)d_in[0];
    const float* B0 = (const float*)d_in[1];
    const float* A1 = (const float*)d_in[2];
    const float* B1 = (const float*)d_in[3];
    const float* A2 = (const float*)d_in[4];
    const float* B2 = (const float*)d_in[5];
    const float* A3 = (const float*)d_in[6];
    const float* B3 = (const float*)d_in[7];
    float* out = (float*)d_out;
    float* cgbuf = (float*)d_ws;

    const int N = in_sizes[0] / 32;  // A0 is (2, N, 1, 16)

    // CG table must be rebuilt every call (d_ws re-poisoned before each run).
    hipLaunchKernelGGL(cg_init_kernel, dim3(14), dim3(256), 0, stream, cgbuf);

    // pair counts per output degree
    int npairs[4] = {0, 0, 0, 0};
    for (int l1 = 0; l1 <= 3; ++l1)
    for (int l2 = 0; l2 <= 3; ++l2) {
        int lo = (l1 > l2) ? (l1 - l2) : (l2 - l1);
        int hi = (l1 + l2 < 3) ? (l1 + l2) : 3;
        for (int l = lo; l <= hi; ++l) npairs[l]++;
    }

    long base = 0;
    for (int L = 0; L < 4; ++L) {
        const int CHL = npairs[L] * 256;
        const long quads = (long)npairs[L] * N * (2 * L + 1) * 64;
        const int blocks = (int)(quads / 256);
        switch (L) {
            case 0:
                hipLaunchKernelGGL((cg_prod_kernel<0>), dim3(blocks), dim3(256), 0, stream,
                                   A0, A1, A2, A3, B0, B1, B2, B3, cgbuf, out, N, base, CHL);
                break;
            case 1:
                hipLaunchKernelGGL((cg_prod_kernel<1>), dim3(blocks), dim3(256), 0, stream,
                                   A0, A1, A2, A3, B0, B1, B2, B3, cgbuf, out, N, base, CHL);
                break;
            case 2:
                hipLaunchKernelGGL((cg_prod_kernel<2>), dim3(blocks), dim3(256), 0, stream,
                                   A0, A1, A2, A3, B0, B1, B2, B3, cgbuf, out, N, base, CHL);
                break;
            case 3:
                hipLaunchKernelGGL((cg_prod_kernel<3>), dim3(blocks), dim3(256), 0, stream,
                                   A0, A1, A2, A3, B0, B1, B2, B3, cgbuf, out, N, base, CHL);
                break;
        }
        base += (long)2 * N * (2 * L + 1) * CHL;
    }
}